// Round 3
// baseline (186.166 us; speedup 1.0000x reference)
//
#include <hip/hip_runtime.h>

#define B_  8
#define K_  256
#define C_  8
#define PS  64
#define H_  512
#define W_  512
#define HW_ (H_ * W_)
#define TH  32
#define TW  32

// Detect whether coords buffer is int64 (little-endian lo/hi pairs, hi==0 since
// coords are small non-negative) or already int32; write decoded int32 coords.
__global__ void decode_coords_kernel(const int* __restrict__ raw,
                                     int* __restrict__ coords, int n) {
    __shared__ int s_nonzero;
    if (threadIdx.x == 0) s_nonzero = 0;
    __syncthreads();
    int local = 0;
    for (int i = 2 * threadIdx.x + 1; i < n; i += 2 * blockDim.x) {
        if (raw[i] != 0) local = 1;
    }
    if (local) atomicOr(&s_nonzero, 1);
    __syncthreads();
    bool is64 = (s_nonzero == 0);  // all odd words zero -> int64 layout
    for (int i = threadIdx.x; i < n; i += blockDim.x) {
        coords[i] = is64 ? raw[2 * i] : raw[i];
    }
}

// Gather: one block per 32x32 output tile. Phase 1: ordered compaction of the
// ~12 intersecting patches into an LDS list (ballot + cross-wave prefix).
// Phase 2: branchless gather — offsets wrapped with &63 (always in-bounds),
// contribution masked by a validity flag; 32 loads per patch staged into
// registers as one cluster for maximum memory-level parallelism. No atomics.
__global__ __launch_bounds__(256)
void gather_kernel(const float* __restrict__ logits,
                   const int* __restrict__ coords,
                   float* __restrict__ out) {
    const int b   = blockIdx.z;
    const int ty0 = blockIdx.y * TH;
    const int tx0 = blockIdx.x * TW;
    const int tid = threadIdx.x;

    __shared__ int2 s_coords[K_];
    __shared__ int  s_list[K_];
    __shared__ unsigned long long s_mask[4];

    // --- Phase 1: ordered accept-list compaction (one coord per thread) ---
    {
        int2 cc = ((const int2*)coords)[b * K_ + tid];
        s_coords[tid] = cc;
        bool hit = (cc.x < ty0 + TH) && (cc.x + PS > ty0) &&
                   (cc.y < tx0 + TW) && (cc.y + PS > tx0);
        unsigned long long m = __ballot(hit);
        const int wid = tid >> 6, lane = tid & 63;
        if (lane == 0) s_mask[wid] = m;
        __syncthreads();
        int base = 0;
        for (int w = 0; w < wid; ++w) base += __popcll(s_mask[w]);
        if (hit) {
            int pos = base + __popcll(m & ((1ull << lane) - 1ull));
            s_list[pos] = tid;
        }
    }
    int nacc = 0;
    for (int w = 0; w < 4; ++w) nacc += __popcll(s_mask[w]);
    __syncthreads();

    // --- Phase 2: branchless register-accumulated gather ---
    float accv[4][C_];
    float cnt[4];
#pragma unroll
    for (int j = 0; j < 4; ++j) {
        cnt[j] = 0.0f;
#pragma unroll
        for (int ch = 0; ch < C_; ++ch) accv[j][ch] = 0.0f;
    }

    const int x  = tx0 + (tid & 31);   // same x for all 4 owned pixels
    const int y0 = ty0 + (tid >> 5);   // rows y0, y0+8, y0+16, y0+24

    for (int t = 0; t < nacc; ++t) {
        const int k = s_list[t];
        const int r = s_coords[k].x;
        const int c = s_coords[k].y;
        const float* __restrict__ pbase =
            logits + (((size_t)(b * K_ + k)) << 15);  // * C*ps*ps

        const int  px  = x - c;
        const bool okx = (unsigned)px < PS;
        const int  pxw = px & (PS - 1);

        float f[4];
        int   off[4];
#pragma unroll
        for (int j = 0; j < 4; ++j) {
            const int py = y0 + j * 8 - r;
            const bool ok = okx && ((unsigned)py < PS);
            f[j]   = ok ? 1.0f : 0.0f;
            off[j] = ((py & (PS - 1)) << 6) | pxw;  // always in-bounds
        }

        float v[4][C_];
#pragma unroll
        for (int j = 0; j < 4; ++j)
#pragma unroll
            for (int ch = 0; ch < C_; ++ch)
                v[j][ch] = pbase[((size_t)ch << 12) + off[j]];

#pragma unroll
        for (int j = 0; j < 4; ++j) {
            cnt[j] += f[j];
#pragma unroll
            for (int ch = 0; ch < C_; ++ch)
                accv[j][ch] = fmaf(v[j][ch], f[j], accv[j][ch]);
        }
    }

    // --- Fused finalize + store (each output pixel written exactly once) ---
#pragma unroll
    for (int j = 0; j < 4; ++j) {
        const int y = y0 + j * 8;
        const bool covered = cnt[j] > 1e-6f;
        const float inv = 1.0f / fmaxf(cnt[j], 1e-6f);
#pragma unroll
        for (int ch = 0; ch < C_; ++ch) {
            const float v = covered ? accv[j][ch] * inv : -10.0f;
            out[(((size_t)(b * C_ + ch)) << 18) + y * W_ + x] = v;
        }
    }
}

extern "C" void kernel_launch(void* const* d_in, const int* in_sizes, int n_in,
                              void* d_out, int out_size, void* d_ws, size_t ws_size,
                              hipStream_t stream) {
    const float* logits = (const float*)d_in[0];
    const int* raw_coords = (const int*)d_in[1];
    float* out = (float*)d_out;

    int* coords = (int*)d_ws;  // 16 KiB decoded coords

    decode_coords_kernel<<<1, 256, 0, stream>>>(raw_coords, coords, B_ * K_ * 2);

    dim3 grid(W_ / TW, H_ / TH, B_);  // 16 x 16 x 8 = 2048 blocks
    gather_kernel<<<grid, 256, 0, stream>>>(logits, coords, out);
}

// Round 4
// 106.626 us; speedup vs baseline: 1.7460x; 1.7460x over previous
//
#include <hip/hip_runtime.h>

#define B_  8
#define K_  256
#define C_  8
#define PS  64
#define H_  512
#define W_  512
#define TH  32
#define TW  32

// Detect whether coords buffer is int64 (little-endian lo/hi pairs, hi==0 since
// coords are small non-negative) or already int32; write decoded int32 coords.
__global__ void decode_coords_kernel(const int* __restrict__ raw,
                                     int* __restrict__ coords, int n) {
    __shared__ int s_nonzero;
    if (threadIdx.x == 0) s_nonzero = 0;
    __syncthreads();
    int local = 0;
    for (int i = 2 * threadIdx.x + 1; i < n; i += 2 * blockDim.x) {
        if (raw[i] != 0) local = 1;
    }
    if (local) atomicOr(&s_nonzero, 1);
    __syncthreads();
    bool is64 = (s_nonzero == 0);  // all odd words zero -> int64 layout
    for (int i = threadIdx.x; i < n; i += blockDim.x) {
        coords[i] = is64 ? raw[2 * i] : raw[i];
    }
}

// Gather: one block per 32x32 output tile. Phase 1: ordered compaction of the
// ~12 intersecting patches. Phase 2: per patch, 32 UNCONDITIONAL loads with
// offsets CLAMPED into the overlap window [pxlo,pxhi]x[pylo,pyhi] — invalid
// lanes re-load boundary cachelines (no extra HBM lines, unlike the R3 wrap),
// masked accumulate via a validity flag. Patch scalars forced to SGPR via
// readfirstlane; unroll-2 over patches for ~64 loads in flight per wave.
__global__ __launch_bounds__(256)
void gather_kernel(const float* __restrict__ logits,
                   const int* __restrict__ coords,
                   float* __restrict__ out) {
    const int b   = blockIdx.z;
    const int ty0 = blockIdx.y * TH;
    const int tx0 = blockIdx.x * TW;
    const int tid = threadIdx.x;

    __shared__ int2 s_rc[K_];   // accepted (r,c), compacted in k-order
    __shared__ int  s_k[K_];    // accepted patch index
    __shared__ unsigned long long s_mask[4];

    // --- Phase 1: ordered accept-list compaction (one coord per thread) ---
    {
        int2 cc = ((const int2*)coords)[b * K_ + tid];
        bool hit = (cc.x < ty0 + TH) && (cc.x + PS > ty0) &&
                   (cc.y < tx0 + TW) && (cc.y + PS > tx0);
        unsigned long long m = __ballot(hit);
        const int wid = tid >> 6, lane = tid & 63;
        if (lane == 0) s_mask[wid] = m;
        __syncthreads();
        int base = 0;
        for (int w = 0; w < wid; ++w) base += __popcll(s_mask[w]);
        if (hit) {
            int pos = base + __popcll(m & ((1ull << lane) - 1ull));
            s_rc[pos] = cc;
            s_k[pos]  = tid;
        }
    }
    int nacc = 0;
    for (int w = 0; w < 4; ++w) nacc += __popcll(s_mask[w]);
    __syncthreads();

    // --- Phase 2: clamped-address clustered gather ---
    float acc[4][C_];
    float cnt[4];
#pragma unroll
    for (int j = 0; j < 4; ++j) {
        cnt[j] = 0.0f;
#pragma unroll
        for (int ch = 0; ch < C_; ++ch) acc[j][ch] = 0.0f;
    }

    const int x  = tx0 + (tid & 31);   // owned column
    const int y0 = ty0 + (tid >> 5);   // owned rows: y0 + {0,8,16,24}

#pragma unroll 2
    for (int t = 0; t < nacc; ++t) {
        const int k = __builtin_amdgcn_readfirstlane(s_k[t]);
        const int r = __builtin_amdgcn_readfirstlane(s_rc[t].x);
        const int c = __builtin_amdgcn_readfirstlane(s_rc[t].y);
        const float* __restrict__ pbase =
            logits + (((size_t)(b * K_ + k)) << 15);  // * C*ps*ps

        // Valid overlap window in patch coords (non-empty by construction).
        const int pxlo = max(0, tx0 - c);
        const int pxhi = min(PS - 1, tx0 + TW - 1 - c);
        const int pylo = max(0, ty0 - r);
        const int pyhi = min(PS - 1, ty0 + TH - 1 - r);

        const int  px  = x - c;
        const int  pxc = min(max(px, pxlo), pxhi);
        const bool okx = (px == pxc);

        float f[4];
        int   off[4];
#pragma unroll
        for (int j = 0; j < 4; ++j) {
            const int py  = y0 + j * 8 - r;
            const int pyc = min(max(py, pylo), pyhi);
            f[j]   = (okx && (py == pyc)) ? 1.0f : 0.0f;
            off[j] = (pyc << 6) + pxc;   // inside overlap window, always fetched
        }

        float v[4][C_];
#pragma unroll
        for (int j = 0; j < 4; ++j)
#pragma unroll
            for (int ch = 0; ch < C_; ++ch)
                v[j][ch] = pbase[((size_t)ch << 12) + off[j]];

#pragma unroll
        for (int j = 0; j < 4; ++j) {
            cnt[j] += f[j];
#pragma unroll
            for (int ch = 0; ch < C_; ++ch)
                acc[j][ch] = fmaf(v[j][ch], f[j], acc[j][ch]);
        }
    }

    // --- Fused finalize + store (each output pixel written exactly once) ---
#pragma unroll
    for (int j = 0; j < 4; ++j) {
        const int y = y0 + j * 8;
        const bool covered = cnt[j] > 1e-6f;
        const float inv = 1.0f / fmaxf(cnt[j], 1e-6f);
#pragma unroll
        for (int ch = 0; ch < C_; ++ch) {
            const float v = covered ? acc[j][ch] * inv : -10.0f;
            out[(((size_t)(b * C_ + ch)) << 18) + y * W_ + x] = v;
        }
    }
}

extern "C" void kernel_launch(void* const* d_in, const int* in_sizes, int n_in,
                              void* d_out, int out_size, void* d_ws, size_t ws_size,
                              hipStream_t stream) {
    const float* logits = (const float*)d_in[0];
    const int* raw_coords = (const int*)d_in[1];
    float* out = (float*)d_out;

    int* coords = (int*)d_ws;  // 16 KiB decoded coords

    decode_coords_kernel<<<1, 256, 0, stream>>>(raw_coords, coords, B_ * K_ * 2);

    dim3 grid(W_ / TW, H_ / TH, B_);  // 16 x 16 x 8 = 2048 blocks
    gather_kernel<<<grid, 256, 0, stream>>>(logits, coords, out);
}

// Round 5
// 103.972 us; speedup vs baseline: 1.7905x; 1.0255x over previous
//
#include <hip/hip_runtime.h>

#define B_  8
#define K_  256
#define C_  8
#define PS  64
#define H_  512
#define W_  512
#define TH  32
#define TW  32

// Detect whether coords buffer is int64 (little-endian lo/hi pairs, hi==0 since
// coords are small non-negative) or already int32; write decoded int32 coords.
__global__ void decode_coords_kernel(const int* __restrict__ raw,
                                     int* __restrict__ coords, int n) {
    __shared__ int s_nonzero;
    if (threadIdx.x == 0) s_nonzero = 0;
    __syncthreads();
    int local = 0;
    for (int i = 2 * threadIdx.x + 1; i < n; i += 2 * blockDim.x) {
        if (raw[i] != 0) local = 1;
    }
    if (local) atomicOr(&s_nonzero, 1);
    __syncthreads();
    bool is64 = (s_nonzero == 0);  // all odd words zero -> int64 layout
    for (int i = threadIdx.x; i < n; i += blockDim.x) {
        coords[i] = is64 ? raw[2 * i] : raw[i];
    }
}

// Gather: one block per 32x32 output tile. Phase 1: ordered compaction of the
// ~12 intersecting patches. Phase 2: clamped-address gather (R4) with an
// EXPLICIT 2-deep software pipeline: named double-buffers vA/vB so 32-64
// loads stay in flight per wave. __launch_bounds__(256,3) gives the register
// allocator ~170 VGPRs so the pipeline isn't silently serialized (R4 got only
// 56 VGPRs and split the load clusters). No atomics.
__global__ __launch_bounds__(256, 3)
void gather_kernel(const float* __restrict__ logits,
                   const int* __restrict__ coords,
                   float* __restrict__ out) {
    const int b   = blockIdx.z;
    const int ty0 = blockIdx.y * TH;
    const int tx0 = blockIdx.x * TW;
    const int tid = threadIdx.x;

    __shared__ int2 s_rc[K_];   // accepted (r,c), compacted in k-order
    __shared__ int  s_k[K_];    // accepted patch index
    __shared__ unsigned long long s_mask[4];

    // --- Phase 1: ordered accept-list compaction (one coord per thread) ---
    {
        int2 cc = ((const int2*)coords)[b * K_ + tid];
        bool hit = (cc.x < ty0 + TH) && (cc.x + PS > ty0) &&
                   (cc.y < tx0 + TW) && (cc.y + PS > tx0);
        unsigned long long m = __ballot(hit);
        const int wid = tid >> 6, lane = tid & 63;
        if (lane == 0) s_mask[wid] = m;
        __syncthreads();
        int base = 0;
        for (int w = 0; w < wid; ++w) base += __popcll(s_mask[w]);
        if (hit) {
            int pos = base + __popcll(m & ((1ull << lane) - 1ull));
            s_rc[pos] = cc;
            s_k[pos]  = tid;
        }
    }
    int nacc = 0;
    for (int w = 0; w < 4; ++w) nacc += __popcll(s_mask[w]);
    __syncthreads();

    // --- Phase 2: software-pipelined clamped-address gather ---
    float acc[4][C_];
    float cnt[4];
#pragma unroll
    for (int j = 0; j < 4; ++j) {
        cnt[j] = 0.0f;
#pragma unroll
        for (int ch = 0; ch < C_; ++ch) acc[j][ch] = 0.0f;
    }

    const int x  = tx0 + (tid & 31);   // owned column
    const int y0 = ty0 + (tid >> 5);   // owned rows: y0 + {0,8,16,24}

#define PREP(T, BASE, OFF, F)                                               \
    {                                                                       \
        const int k_ = __builtin_amdgcn_readfirstlane(s_k[(T)]);            \
        const int r_ = __builtin_amdgcn_readfirstlane(s_rc[(T)].x);         \
        const int c_ = __builtin_amdgcn_readfirstlane(s_rc[(T)].y);         \
        BASE = logits + (((size_t)(b * K_ + k_)) << 15);                    \
        const int pxlo = max(0, tx0 - c_);                                  \
        const int pxhi = min(PS - 1, tx0 + TW - 1 - c_);                    \
        const int pylo = max(0, ty0 - r_);                                  \
        const int pyhi = min(PS - 1, ty0 + TH - 1 - r_);                    \
        const int px   = x - c_;                                            \
        const int pxc  = min(max(px, pxlo), pxhi);                          \
        const bool okx = (px == pxc);                                       \
        _Pragma("unroll")                                                   \
        for (int j = 0; j < 4; ++j) {                                       \
            const int py  = y0 + j * 8 - r_;                                \
            const int pyc = min(max(py, pylo), pyhi);                       \
            F[j]   = (okx && (py == pyc)) ? 1.0f : 0.0f;                    \
            OFF[j] = (pyc << 6) + pxc;                                      \
        }                                                                   \
    }

#define LOADV(V, BASE, OFF)                                                 \
    _Pragma("unroll")                                                       \
    for (int j = 0; j < 4; ++j) {                                           \
        _Pragma("unroll")                                                   \
        for (int ch = 0; ch < C_; ++ch)                                     \
            V[j][ch] = BASE[((size_t)ch << 12) + OFF[j]];                   \
    }

#define ACCUM(V, F)                                                         \
    _Pragma("unroll")                                                       \
    for (int j = 0; j < 4; ++j) {                                           \
        cnt[j] += F[j];                                                     \
        _Pragma("unroll")                                                   \
        for (int ch = 0; ch < C_; ++ch)                                     \
            acc[j][ch] = fmaf(V[j][ch], F[j], acc[j][ch]);                  \
    }

    float vA[4][C_], vB[4][C_];
    float fA[4], fB[4];
    int   offA[4], offB[4];
    const float* baseA;
    const float* baseB;

    int t = 0;
    if (nacc > 0) { PREP(0, baseA, offA, fA); LOADV(vA, baseA, offA); }
    while (t + 1 < nacc) {
        PREP(t + 1, baseB, offB, fB);
        LOADV(vB, baseB, offB);      // B in flight while we consume A
        ACCUM(vA, fA);
        ++t;
        if (t + 1 < nacc) {
            PREP(t + 1, baseA, offA, fA);
            LOADV(vA, baseA, offA);  // A in flight while we consume B
        }
        ACCUM(vB, fB);
        ++t;
    }
    if (t < nacc) ACCUM(vA, fA);     // odd tail (vA already loaded)

    // --- Fused finalize + store (each output pixel written exactly once) ---
#pragma unroll
    for (int j = 0; j < 4; ++j) {
        const int y = y0 + j * 8;
        const bool covered = cnt[j] > 1e-6f;
        const float inv = 1.0f / fmaxf(cnt[j], 1e-6f);
#pragma unroll
        for (int ch = 0; ch < C_; ++ch) {
            const float v = covered ? acc[j][ch] * inv : -10.0f;
            out[(((size_t)(b * C_ + ch)) << 18) + y * W_ + x] = v;
        }
    }
}

extern "C" void kernel_launch(void* const* d_in, const int* in_sizes, int n_in,
                              void* d_out, int out_size, void* d_ws, size_t ws_size,
                              hipStream_t stream) {
    const float* logits = (const float*)d_in[0];
    const int* raw_coords = (const int*)d_in[1];
    float* out = (float*)d_out;

    int* coords = (int*)d_ws;  // 16 KiB decoded coords

    decode_coords_kernel<<<1, 256, 0, stream>>>(raw_coords, coords, B_ * K_ * 2);

    dim3 grid(W_ / TW, H_ / TH, B_);  // 16 x 16 x 8 = 2048 blocks
    gather_kernel<<<grid, 256, 0, stream>>>(logits, coords, out);
}